// Round 7
// baseline (165.814 us; speedup 1.0000x reference)
//
#include <hip/hip_runtime.h>

#define B_   16
#define S_   128
#define R_   1024
#define KIN  25
#define H_   128
#define MID  256
#define KP   160    // weight K stride (10 blocks of 16)
#define KLH  132    // A row stride (halves): 66 dw -> 2-way banks (free), 8B aligned
#define XA   36     // x-arena row stride
#define ROWS 32
#define NT   4      // i-tiles per wave (4 x 32 = 128 h-dims)

typedef _Float16 h8  __attribute__((ext_vector_type(8)));
typedef _Float16 h4  __attribute__((ext_vector_type(4)));
typedef _Float16 h2  __attribute__((ext_vector_type(2)));
typedef float    f16v __attribute__((ext_vector_type(16)));
typedef float    f4v  __attribute__((ext_vector_type(4)));

__device__ __forceinline__ h2 pk2(float a, float b) {
    auto r = __builtin_amdgcn_cvt_pkrtz(a, b);
    h2 o; o[0] = (_Float16)r[0]; o[1] = (_Float16)r[1]; return o;
}

// inter k-order: [h(0..127) | x(128..152) | c(153) | pad(154..159)]
__device__ __forceinline__ int orig_k(int kp) {
    if (kp < H_)        return KIN + kp;
    if (kp < H_ + KIN)  return kp - H_;
    if (kp == H_ + KIN) return H_ + KIN;
    return -1;
}

// ---------------------------------------------------------------------------
__global__ void prep_kernel(const float* __restrict__ Wo1, const float* __restrict__ Wo2,
                            const float* __restrict__ Wh1, const float* __restrict__ Wh2,
                            _Float16* __restrict__ WTP, _Float16* __restrict__ woP)
{
    const int kp = blockIdx.x;
    const int t  = threadIdx.x;            // 128 threads
    if (kp < KP) {
        const int ok = orig_k(kp);
        float acc = 0.f;
        if (ok >= 0) {
            const float* w1 = Wh1 + (long)ok * MID;
            for (int m = 0; m < MID; ++m)
                acc += w1[m] * Wh2[m * H_ + t];
        }
        WTP[t * KP + kp] = (_Float16)acc;
    } else {
#pragma unroll
        for (int r = 0; r < 2; ++r) {
            int k2 = t + r * 128;
            if (k2 < KP) {
                int ok = orig_k(k2);
                float acc = 0.f;
                if (ok >= 0)
                    for (int m = 0; m < MID; ++m)
                        acc += Wo1[ok * MID + m] * Wo2[m];
                woP[k2] = (_Float16)acc;
            }
        }
    }
}

// ---------------------------------------------------------------------------
// 512 blocks x 64 thr: ONE wave per block, 32 rows, all 128 i-dims (4 tiles).
// Barrier-free: intra-wave LDS ordering is the only sync. 4-step unroll makes
// all LDS buffer indices compile-time constants.
// ---------------------------------------------------------------------------
__global__ __launch_bounds__(64, 1) void rnn_main(
    const float* __restrict__ x, const float* __restrict__ hidden,
    const float* __restrict__ cost, const _Float16* __restrict__ WTP,
    const _Float16* __restrict__ woP, float* __restrict__ outs,
    float* __restrict__ hfin)
{
    __shared__ _Float16 A[2][ROWS][KLH];        // 16,896 B (h, double-buffered)
    __shared__ _Float16 xar[2][2][ROWS][XA];    //  9,216 B (x+c, 2 slots x 2 steps)

    const int t  = threadIdx.x;
    const int n  = t & 31, hi = t >> 5;
    const int b  = blockIdx.x >> 5;
    const int r0 = (blockIdx.x & 31) << 5;

    // ---- weights into registers ----
    h8 af[NT][10], wof[10];
#pragma unroll
    for (int tile = 0; tile < NT; ++tile)
#pragma unroll
        for (int kb = 0; kb < 10; ++kb)
            af[tile][kb] = *reinterpret_cast<const h8*>(
                &WTP[(tile * 32 + n) * KP + kb * 16 + hi * 8]);
#pragma unroll
    for (int kb = 0; kb < 10; ++kb)
        wof[kb] = *reinterpret_cast<const h8*>(&woP[kb * 16 + hi * 8]);

    f16v zero16;
#pragma unroll
    for (int i = 0; i < 16; ++i) zero16[i] = 0.f;

    // ---- zero arena pad cols 26..35 (2 slots x 2 subs x 32 rows = 128 rows) ----
#pragma unroll
    for (int z = 0; z < 2; ++z) {
        int row = t + z * 64;
        _Float16* rp = &xar[row >> 6][(row >> 5) & 1][row & 31][0];
#pragma unroll
        for (int c = 26; c < XA; ++c) rp[c] = (_Float16)0.f;
    }

    // ---- h(0) -> A[0]: thread covers row n, 64 cols at hi*64 ----
    {
        const float4* hp = reinterpret_cast<const float4*>(
            hidden + ((long)(b * R_ + r0 + n)) * H_ + hi * 64);
#pragma unroll
        for (int g = 0; g < 16; ++g) {
            float4 p = hp[g];
            h2 c0 = pk2(p.x, p.y), c1 = pk2(p.z, p.w);
            h4 v; v[0] = c0[0]; v[1] = c0[1]; v[2] = c1[0]; v[3] = c1[1];
            *reinterpret_cast<h4*>(&A[0][n][hi * 64 + g * 4]) = v;
        }
    }

    // ---- x pipeline: thread covers (row n, step s0+hi); 2 steps per batch ----
    float xrA[25], crA = 0.f, xrB[25], crB = 0.f;

    auto xload = [&](int s0, float* xr, float& cr) {
        int s = s0 + hi;
        if (s < S_) {
            const float* p = x + ((long)(b * S_ + s) * R_ + r0 + n) * KIN;
#pragma unroll
            for (int g = 0; g < 6; ++g) {
                float4 v = *reinterpret_cast<const float4*>(p + g * 4);
                xr[g * 4 + 0] = v.x; xr[g * 4 + 1] = v.y;
                xr[g * 4 + 2] = v.z; xr[g * 4 + 3] = v.w;
            }
            xr[24] = p[24];
            cr = cost[b * S_ + s];
        }
    };
    auto xcvt = [&](int slot, const float* xr, float cr) {
        _Float16* dst = &xar[slot][hi][n][0];
#pragma unroll
        for (int g = 0; g < 6; ++g) {
            h2 a0 = pk2(xr[g * 4 + 0], xr[g * 4 + 1]);
            h2 a1 = pk2(xr[g * 4 + 2], xr[g * 4 + 3]);
            h4 v; v[0] = a0[0]; v[1] = a0[1]; v[2] = a1[0]; v[3] = a1[1];
            *reinterpret_cast<h4*>(&dst[g * 4]) = v;
        }
        h2 tl = pk2(xr[24], cr);
        *reinterpret_cast<h2*>(&dst[24]) = tl;
    };

    xload(0, xrA, crA);
    xcvt(0, xrA, crA);
    xload(2, xrB, crB);

    f16v acc[NT];

// one time-step; J = compile-time 0..3 -> all buffer indices static
#define STEP(J, OG) do {                                                        \
    constexpr int cur_  = (J) & 1, nxt_ = ((J) & 1) ^ 1;                        \
    constexpr int slot_ = ((J) >> 1) & 1, sub_ = (J) & 1;                       \
    h2 po0{}, po1{}, po2{}, po3{};                                              \
    _Pragma("unroll")                                                           \
    for (int kb = 0; kb < 10; ++kb) {                                           \
        h4 lo, hv;                                                              \
        if (kb < 8) {                                                           \
            lo = *reinterpret_cast<const h4*>(&A[cur_][n][kb * 16 + hi * 8]);   \
            hv = *reinterpret_cast<const h4*>(&A[cur_][n][kb * 16 + hi * 8 + 4]); \
        } else {                                                                \
            lo = *reinterpret_cast<const h4*>(&xar[slot_][sub_][n][(kb - 8) * 16 + hi * 8]); \
            hv = *reinterpret_cast<const h4*>(&xar[slot_][sub_][n][(kb - 8) * 16 + hi * 8 + 4]); \
        }                                                                       \
        h8 bf = __builtin_shufflevector(lo, hv, 0, 1, 2, 3, 4, 5, 6, 7);        \
        _Pragma("unroll")                                                       \
        for (int tile = 0; tile < NT; ++tile)                                   \
            acc[tile] = __builtin_amdgcn_mfma_f32_32x32x16_f16(                 \
                af[tile][kb], bf, kb == 0 ? zero16 : acc[tile], 0, 0, 0);       \
        po0 += __builtin_shufflevector(bf, bf, 0, 1) * __builtin_shufflevector(wof[kb], wof[kb], 0, 1); \
        po1 += __builtin_shufflevector(bf, bf, 2, 3) * __builtin_shufflevector(wof[kb], wof[kb], 2, 3); \
        po2 += __builtin_shufflevector(bf, bf, 4, 5) * __builtin_shufflevector(wof[kb], wof[kb], 4, 5); \
        po3 += __builtin_shufflevector(bf, bf, 6, 7) * __builtin_shufflevector(wof[kb], wof[kb], 6, 7); \
    }                                                                           \
    { h2 pa = po0 + po1, pb = po2 + po3, pc = pa + pb;                          \
      OG = (float)pc[0] + (float)pc[1]; }                                       \
    _Pragma("unroll")                                                           \
    for (int tile = 0; tile < NT; ++tile) {                                     \
        _Pragma("unroll")                                                       \
        for (int q2 = 0; q2 < 4; ++q2) {                                        \
            h2 a0 = pk2(acc[tile][q2 * 4 + 0], acc[tile][q2 * 4 + 1]);          \
            h2 a1 = pk2(acc[tile][q2 * 4 + 2], acc[tile][q2 * 4 + 3]);          \
            h4 v; v[0] = a0[0]; v[1] = a0[1]; v[2] = a1[0]; v[3] = a1[1];       \
            *reinterpret_cast<h4*>(&A[nxt_][n][tile * 32 + q2 * 8 + hi * 4]) = v; \
        }                                                                       \
    }                                                                           \
} while (0)

    for (int s4 = 0; s4 < S_; s4 += 4) {
        float og0, og1, og2, og3;
        xcvt(1, xrB, crB);          // arena for steps s4+2, s4+3
        xload(s4 + 4, xrA, crA);    // in flight ~2 steps
        STEP(0, og0);
        STEP(1, og1);
        xcvt(0, xrA, crA);          // arena for steps s4+4, s4+5
        xload(s4 + 6, xrB, crB);
        STEP(2, og2);
        STEP(3, og3);
        og0 += __shfl_xor(og0, 32, 64);
        og1 += __shfl_xor(og1, 32, 64);
        og2 += __shfl_xor(og2, 32, 64);
        og3 += __shfl_xor(og3, 32, 64);
        if (hi == 0) {
            float* op = outs + (long)(b * S_ + s4) * R_ + r0 + n;
            op[0]      = og0;
            op[R_]     = og1;
            op[2 * R_] = og2;
            op[3 * R_] = og3;
        }
    }
#undef STEP

    // ---- h_final from step-127 accumulators (fp32) ----
#pragma unroll
    for (int tile = 0; tile < NT; ++tile)
#pragma unroll
        for (int q2 = 0; q2 < 4; ++q2) {
            f4v v;
            v[0] = acc[tile][q2 * 4 + 0];
            v[1] = acc[tile][q2 * 4 + 1];
            v[2] = acc[tile][q2 * 4 + 2];
            v[3] = acc[tile][q2 * 4 + 3];
            *reinterpret_cast<f4v*>(
                &hfin[((long)(b * R_ + r0 + n)) * H_ + tile * 32 + q2 * 8 + hi * 4]) = v;
        }
}

// ---------------------------------------------------------------------------
extern "C" void kernel_launch(void* const* d_in, const int* in_sizes, int n_in,
                              void* d_out, int out_size, void* d_ws, size_t ws_size,
                              hipStream_t stream)
{
    const float* x      = (const float*)d_in[0];
    const float* hidden = (const float*)d_in[1];
    const float* cost   = (const float*)d_in[2];
    const float* Wo1    = (const float*)d_in[3];
    const float* Wo2    = (const float*)d_in[4];
    const float* Wh1    = (const float*)d_in[5];
    const float* Wh2    = (const float*)d_in[6];

    float* outs = (float*)d_out;                    // [B,S,R]
    float* hfin = outs + (long)B_ * S_ * R_;        // [B,R,H]

    _Float16* WTP = (_Float16*)d_ws;                // [128][160]
    _Float16* woP = WTP + (size_t)H_ * KP;          // [160]

    prep_kernel<<<KP + 1, 128, 0, stream>>>(Wo1, Wo2, Wh1, Wh2, WTP, woP);
    rnn_main<<<512, 64, 0, stream>>>(x, hidden, cost, WTP, woP, outs, hfin);
}

// Round 8
// 161.397 us; speedup vs baseline: 1.0274x; 1.0274x over previous
//
#include <hip/hip_runtime.h>

#define B_   16
#define S_   128
#define R_   1024
#define KIN  25
#define H_   128
#define MID  256
#define KP   160    // weight K stride (10 blocks of 16)
#define XA   36     // x-arena row stride (halves)
#define ROWS 32
#define NT   4      // i-tiles per wave (4 x 32 = 128 h-dims)

typedef _Float16 h8  __attribute__((ext_vector_type(8)));
typedef _Float16 h4  __attribute__((ext_vector_type(4)));
typedef _Float16 h2  __attribute__((ext_vector_type(2)));
typedef float    f16v __attribute__((ext_vector_type(16)));
typedef float    f4v  __attribute__((ext_vector_type(4)));

__device__ __forceinline__ h2 pk2(float a, float b) {
    auto r = __builtin_amdgcn_cvt_pkrtz(a, b);
    h2 o; o[0] = (_Float16)r[0]; o[1] = (_Float16)r[1]; return o;
}
__device__ __forceinline__ unsigned h2u(h2 v) {
    union { h2 h; unsigned u; } c; c.h = v; return c.u;
}
__device__ __forceinline__ h2 u2h(unsigned u) {
    union { h2 h; unsigned u; } c; c.u = u; return c.h;
}
__device__ __forceinline__ h8 mk8(unsigned a, unsigned b, unsigned c, unsigned d) {
    union { h8 v; unsigned u[4]; } r; r.u[0] = a; r.u[1] = b; r.u[2] = c; r.u[3] = d;
    return r.v;
}
__device__ __forceinline__ h4 mk4(unsigned a, unsigned b) {
    union { h4 v; unsigned u[2]; } r; r.u[0] = a; r.u[1] = b; return r.v;
}

// inter k-order: [h(0..127) | x(128..152) | c(153) | pad(154..159)]
__device__ __forceinline__ int orig_k(int kp) {
    if (kp < H_)        return KIN + kp;
    if (kp < H_ + KIN)  return kp - H_;
    if (kp == H_ + KIN) return H_ + KIN;
    return -1;
}

// ---------------------------------------------------------------------------
__global__ void prep_kernel(const float* __restrict__ Wo1, const float* __restrict__ Wo2,
                            const float* __restrict__ Wh1, const float* __restrict__ Wh2,
                            _Float16* __restrict__ WTP, _Float16* __restrict__ woP)
{
    const int kp = blockIdx.x;
    const int t  = threadIdx.x;            // 128 threads
    if (kp < KP) {
        const int ok = orig_k(kp);
        float acc = 0.f;
        if (ok >= 0) {
            const float* w1 = Wh1 + (long)ok * MID;
            for (int m = 0; m < MID; ++m)
                acc += w1[m] * Wh2[m * H_ + t];
        }
        WTP[t * KP + kp] = (_Float16)acc;
    } else {
#pragma unroll
        for (int r = 0; r < 2; ++r) {
            int k2 = t + r * 128;
            if (k2 < KP) {
                int ok = orig_k(k2);
                float acc = 0.f;
                if (ok >= 0)
                    for (int m = 0; m < MID; ++m)
                        acc += Wo1[ok * MID + m] * Wo2[m];
                woP[k2] = (_Float16)acc;
            }
        }
    }
}

// ---------------------------------------------------------------------------
// 512 blocks x 64 thr: one wave owns 32 rows x 128 h-dims. h-recurrence lives
// entirely in registers: MFMA D -> (pk2 + permlane32_swap) -> next B-frag.
// LDS only for the x arena (4 ds_read_b64/step). No barriers, no h round-trip.
// ---------------------------------------------------------------------------
__global__ __launch_bounds__(64, 1) void rnn_main(
    const float* __restrict__ x, const float* __restrict__ hidden,
    const float* __restrict__ cost, const _Float16* __restrict__ WTP,
    const _Float16* __restrict__ woP, float* __restrict__ outs,
    float* __restrict__ hfin)
{
    __shared__ _Float16 xar[2][2][ROWS][XA];    // 9,216 B (x+c, 2 slots x 2 steps)

    const int t  = threadIdx.x;
    const int n  = t & 31, hi = t >> 5;
    const int b  = blockIdx.x >> 5;
    const int r0 = (blockIdx.x & 31) << 5;

    // ---- weights into registers ----
    h8 af[NT][10], wof[10];
#pragma unroll
    for (int tile = 0; tile < NT; ++tile)
#pragma unroll
        for (int kb = 0; kb < 10; ++kb)
            af[tile][kb] = *reinterpret_cast<const h8*>(
                &WTP[(tile * 32 + n) * KP + kb * 16 + hi * 8]);
#pragma unroll
    for (int kb = 0; kb < 10; ++kb)
        wof[kb] = *reinterpret_cast<const h8*>(&woP[kb * 16 + hi * 8]);

    f16v zero16;
#pragma unroll
    for (int i = 0; i < 16; ++i) zero16[i] = 0.f;

    // ---- zero arena pad cols 26..35 ----
#pragma unroll
    for (int z = 0; z < 2; ++z) {
        int row = t + z * 64;
        _Float16* rp = &xar[row >> 6][(row >> 5) & 1][row & 31][0];
#pragma unroll
        for (int c = 26; c < XA; ++c) rp[c] = (_Float16)0.f;
    }

    // ---- h(0) -> bfh directly in B-frag layout ----
    h8 bfh[8];
    {
        const float* hp = hidden + ((long)(b * R_ + r0 + n)) * H_;
#pragma unroll
        for (int kb = 0; kb < 8; ++kb) {
            float4 v0 = *reinterpret_cast<const float4*>(hp + kb * 16 + hi * 8);
            float4 v1 = *reinterpret_cast<const float4*>(hp + kb * 16 + hi * 8 + 4);
            bfh[kb] = mk8(h2u(pk2(v0.x, v0.y)), h2u(pk2(v0.z, v0.w)),
                          h2u(pk2(v1.x, v1.y)), h2u(pk2(v1.z, v1.w)));
        }
    }

    // ---- x pipeline: thread (n, hi) covers (row n, step s0+hi), packed regs ----
    unsigned xpA[13], xpB[13];

    auto xloadp = [&](int s0, unsigned* xp) {
        int s = s0 + hi;
        if (s < S_) {
            const float* p = x + ((long)(b * S_ + s) * R_ + r0 + n) * KIN;
#pragma unroll
            for (int g = 0; g < 6; ++g) {
                float4 v = *reinterpret_cast<const float4*>(p + g * 4);
                xp[g * 2 + 0] = h2u(pk2(v.x, v.y));
                xp[g * 2 + 1] = h2u(pk2(v.z, v.w));
            }
            xp[12] = h2u(pk2(p[24], cost[b * S_ + s]));
        }
    };
    auto xcvtp = [&](int slot, const unsigned* xp) {
        _Float16* dst = &xar[slot][hi][n][0];
#pragma unroll
        for (int g = 0; g < 6; ++g)
            *reinterpret_cast<h4*>(&dst[g * 4]) = mk4(xp[g * 2], xp[g * 2 + 1]);
        *reinterpret_cast<h2*>(&dst[24]) = u2h(xp[12]);
    };

    xloadp(0, xpA);
    xcvtp(0, xpA);
    xloadp(2, xpB);

    f16v acc[NT];

// one time-step; J compile-time 0..3
#define STEP(J, OG) do {                                                        \
    constexpr int slot_ = ((J) >> 1) & 1, sub_ = (J) & 1;                       \
    const _Float16* xr = &xar[slot_][sub_][n][hi * 8];                          \
    h4 x0a = *reinterpret_cast<const h4*>(xr);                                  \
    h4 x0b = *reinterpret_cast<const h4*>(xr + 4);                              \
    h4 x1a = *reinterpret_cast<const h4*>(xr + 16);                             \
    h4 x1b = *reinterpret_cast<const h4*>(xr + 20);                             \
    h8 bx0 = __builtin_shufflevector(x0a, x0b, 0, 1, 2, 3, 4, 5, 6, 7);         \
    h8 bx1 = __builtin_shufflevector(x1a, x1b, 0, 1, 2, 3, 4, 5, 6, 7);         \
    h2 po0{}, po1{}, po2{}, po3{};                                              \
    _Pragma("unroll")                                                           \
    for (int kb = 0; kb < 10; ++kb) {                                           \
        h8 bf = (kb < 8) ? bfh[kb] : (kb == 8 ? bx0 : bx1);                     \
        _Pragma("unroll")                                                       \
        for (int tile = 0; tile < NT; ++tile)                                   \
            acc[tile] = __builtin_amdgcn_mfma_f32_32x32x16_f16(                 \
                af[tile][kb], bf, kb == 0 ? zero16 : acc[tile], 0, 0, 0);       \
        po0 += __builtin_shufflevector(bf, bf, 0, 1) * __builtin_shufflevector(wof[kb], wof[kb], 0, 1); \
        po1 += __builtin_shufflevector(bf, bf, 2, 3) * __builtin_shufflevector(wof[kb], wof[kb], 2, 3); \
        po2 += __builtin_shufflevector(bf, bf, 4, 5) * __builtin_shufflevector(wof[kb], wof[kb], 4, 5); \
        po3 += __builtin_shufflevector(bf, bf, 6, 7) * __builtin_shufflevector(wof[kb], wof[kb], 6, 7); \
    }                                                                           \
    { h2 pa = po0 + po1, pb = po2 + po3, pc = pa + pb;                          \
      OG = (float)pc[0] + (float)pc[1]; }                                       \
    _Pragma("unroll")                                                           \
    for (int tile = 0; tile < NT; ++tile) {                                     \
        _Pragma("unroll")                                                       \
        for (int p = 0; p < 2; ++p) {                                           \
            unsigned A0 = h2u(pk2(acc[tile][(2*p)*4 + 0], acc[tile][(2*p)*4 + 1]));     \
            unsigned A1 = h2u(pk2(acc[tile][(2*p)*4 + 2], acc[tile][(2*p)*4 + 3]));     \
            unsigned B0 = h2u(pk2(acc[tile][(2*p+1)*4 + 0], acc[tile][(2*p+1)*4 + 1])); \
            unsigned B1 = h2u(pk2(acc[tile][(2*p+1)*4 + 2], acc[tile][(2*p+1)*4 + 3])); \
            auto s0_ = __builtin_amdgcn_permlane32_swap(A0, B0, false, false);  \
            auto s1_ = __builtin_amdgcn_permlane32_swap(A1, B1, false, false);  \
            bfh[tile * 2 + p] = mk8(s0_[0], s1_[0], s0_[1], s1_[1]);            \
        }                                                                       \
    }                                                                           \
} while (0)

    for (int s4 = 0; s4 < S_; s4 += 4) {
        float og0, og1, og2, og3;
        xcvtp(1, xpB);              // arena for steps s4+2, s4+3
        xloadp(s4 + 4, xpA);
        STEP(0, og0);
        STEP(1, og1);
        xcvtp(0, xpA);              // arena for steps s4+4, s4+5
        xloadp(s4 + 6, xpB);
        STEP(2, og2);
        STEP(3, og3);
        og0 += __shfl_xor(og0, 32, 64);
        og1 += __shfl_xor(og1, 32, 64);
        og2 += __shfl_xor(og2, 32, 64);
        og3 += __shfl_xor(og3, 32, 64);
        if (hi == 0) {
            float* op = outs + (long)(b * S_ + s4) * R_ + r0 + n;
            op[0]      = og0;
            op[R_]     = og1;
            op[2 * R_] = og2;
            op[3 * R_] = og3;
        }
    }
#undef STEP

    // ---- h_final from step-127 accumulators (fp32) ----
#pragma unroll
    for (int tile = 0; tile < NT; ++tile)
#pragma unroll
        for (int q2 = 0; q2 < 4; ++q2) {
            f4v v;
            v[0] = acc[tile][q2 * 4 + 0];
            v[1] = acc[tile][q2 * 4 + 1];
            v[2] = acc[tile][q2 * 4 + 2];
            v[3] = acc[tile][q2 * 4 + 3];
            *reinterpret_cast<f4v*>(
                &hfin[((long)(b * R_ + r0 + n)) * H_ + tile * 32 + q2 * 8 + hi * 4]) = v;
        }
}

// ---------------------------------------------------------------------------
extern "C" void kernel_launch(void* const* d_in, const int* in_sizes, int n_in,
                              void* d_out, int out_size, void* d_ws, size_t ws_size,
                              hipStream_t stream)
{
    const float* x      = (const float*)d_in[0];
    const float* hidden = (const float*)d_in[1];
    const float* cost   = (const float*)d_in[2];
    const float* Wo1    = (const float*)d_in[3];
    const float* Wo2    = (const float*)d_in[4];
    const float* Wh1    = (const float*)d_in[5];
    const float* Wh2    = (const float*)d_in[6];

    float* outs = (float*)d_out;                    // [B,S,R]
    float* hfin = outs + (long)B_ * S_ * R_;        // [B,R,H]

    _Float16* WTP = (_Float16*)d_ws;                // [128][160]
    _Float16* woP = WTP + (size_t)H_ * KP;          // [160]

    prep_kernel<<<KP + 1, 128, 0, stream>>>(Wo1, Wo2, Wh1, Wh2, WTP, woP);
    rnn_main<<<512, 64, 0, stream>>>(x, hidden, cost, WTP, woP, outs, hfin);
}

// Round 9
// 115.921 us; speedup vs baseline: 1.4304x; 1.3923x over previous
//
#include <hip/hip_runtime.h>

#define B_   16
#define S_   128
#define R_   1024
#define KIN  25
#define H_   128
#define MID  256
#define KP   160     // weight K stride (5 slabs of 32)
#define SCR  68      // LDS scratch row stride in dwords (16B-aligned reads, bank spread)

typedef _Float16 h8 __attribute__((ext_vector_type(8)));
typedef _Float16 h4 __attribute__((ext_vector_type(4)));
typedef _Float16 h2 __attribute__((ext_vector_type(2)));
typedef float    f4v __attribute__((ext_vector_type(4)));

__device__ __forceinline__ h2 pk2(float a, float b) {
    auto r = __builtin_amdgcn_cvt_pkrtz(a, b);
    h2 o; o[0] = (_Float16)r[0]; o[1] = (_Float16)r[1]; return o;
}
__device__ __forceinline__ unsigned h2u(h2 v) {
    union { h2 h; unsigned u; } c; c.h = v; return c.u;
}
__device__ __forceinline__ h8 mk8(unsigned a, unsigned b, unsigned c, unsigned d) {
    union { h8 v; unsigned u[4]; } r; r.u[0] = a; r.u[1] = b; r.u[2] = c; r.u[3] = d;
    return r.v;
}

// inter k-order: [h(0..127) | x(128..152) | c(153) | pad(154..159)]
__device__ __forceinline__ int orig_k(int kp) {
    if (kp < H_)        return KIN + kp;
    if (kp < H_ + KIN)  return kp - H_;
    if (kp == H_ + KIN) return H_ + KIN;
    return -1;
}

// ---------------------------------------------------------------------------
__global__ void prep_kernel(const float* __restrict__ Wo1, const float* __restrict__ Wo2,
                            const float* __restrict__ Wh1, const float* __restrict__ Wh2,
                            _Float16* __restrict__ WTP, _Float16* __restrict__ woP)
{
    const int kp = blockIdx.x;
    const int t  = threadIdx.x;            // 128 threads
    if (kp < KP) {
        const int ok = orig_k(kp);
        float acc = 0.f;
        if (ok >= 0) {
            const float* w1 = Wh1 + (long)ok * MID;
            for (int m = 0; m < MID; ++m)
                acc += w1[m] * Wh2[m * H_ + t];
        }
        WTP[t * KP + kp] = (_Float16)acc;
    } else {
#pragma unroll
        for (int r = 0; r < 2; ++r) {
            int k2 = t + r * 128;
            if (k2 < KP) {
                int ok = orig_k(k2);
                float acc = 0.f;
                if (ok >= 0)
                    for (int m = 0; m < MID; ++m)
                        acc += Wo1[ok * MID + m] * Wo2[m];
                woP[k2] = (_Float16)acc;
            }
        }
    }
}

// ---------------------------------------------------------------------------
// 1024 blocks x 64 thr: 1024 waves = one per SIMD (full chip). Each wave owns
// a 16-row chain, all 128 h-dims (8 tiles of mfma_f32_16x16x32_f16).
// h handoff D->B via 4.3KB per-wave LDS scratch, loop-invariant addresses.
// No barriers. x loaded per-lane directly in B-frag layout, 2-step prefetch.
// ---------------------------------------------------------------------------
__global__ __launch_bounds__(64, 1) void rnn_main(
    const float* __restrict__ x, const float* __restrict__ hidden,
    const float* __restrict__ cost, const _Float16* __restrict__ WTP,
    const _Float16* __restrict__ woP, float* __restrict__ outs,
    float* __restrict__ hfin)
{
    __shared__ unsigned scr[16 * SCR];   // 4352 B

    const int t = threadIdx.x;
    const int c = t & 15, g = t >> 4;
    const int b  = blockIdx.x >> 6;
    const int r0 = (blockIdx.x & 63) << 4;

    // ---- weights into registers ----
    // A-frag: lane (c,g) holds W[m = it*16 + c][k = kb*32 + g*8 + u]
    h8 af[8][5];
#pragma unroll
    for (int it = 0; it < 8; ++it)
#pragma unroll
        for (int kb = 0; kb < 5; ++kb)
            af[it][kb] = *reinterpret_cast<const h8*>(
                &WTP[(it * 16 + c) * KP + kb * 32 + g * 8]);
    h8 wof[5];
#pragma unroll
    for (int kb = 0; kb < 5; ++kb)
        wof[kb] = *reinterpret_cast<const h8*>(&woP[kb * 32 + g * 8]);

    // ---- scratch addresses (loop-invariant) ----
    // write: P[it] (2 dw) at dw = c*SCR + it*8 + g*2   (offset it*32 B)
    // read:  bf[kb] (4 dw) at dw = c*SCR + 16*kb + 8*(g>>1) + 4*(g&1)
    unsigned* wbase = &scr[c * SCR + g * 2];
    const unsigned* rbase = &scr[c * SCR + 8 * (g >> 1) + 4 * (g & 1)];

    // ---- h(0) -> bf (B-frag layout: lane (c,g): inter[row c][k=kb*32+g*8+u]) ----
    h8 bf[4];
    {
        const float* hp = hidden + ((long)(b * R_ + r0 + c)) * H_;
#pragma unroll
        for (int kb = 0; kb < 4; ++kb) {
            float4 v0 = *reinterpret_cast<const float4*>(hp + kb * 32 + g * 8);
            float4 v1 = *reinterpret_cast<const float4*>(hp + kb * 32 + g * 8 + 4);
            bf[kb] = mk8(h2u(pk2(v0.x, v0.y)), h2u(pk2(v0.z, v0.w)),
                         h2u(pk2(v1.x, v1.y)), h2u(pk2(v1.z, v1.w)));
        }
    }

    // ---- x pipeline: lane (c,g) loads its own B-frag slice of x[s][row c] ----
    const int xoff  = (g == 3) ? 21 : g * 8;     // g=3 reads x[21..24] (use .w)
    const int xoff2 = (g == 3) ? 0 : 4;
    const float* xlane = x + (((long)b * S_) * R_ + r0 + c) * KIN + xoff;

    float4 xv0A, xv1A, xv0B, xv1B;
    float  csA = 0.f, csB = 0.f;
    auto xissue = [&](int s, float4& v0, float4& v1, float& cs) {
        if (s < S_) {
            const float* p = xlane + (long)s * (R_ * KIN);
            v0 = *reinterpret_cast<const float4*>(p);
            v1 = *reinterpret_cast<const float4*>(p + xoff2);
            cs = cost[b * S_ + s];
        }
    };
    auto mkbx = [&](float4 v0, float4 v1, float cs) -> h8 {
        h2 z{};
        h2 d0 = (g == 3) ? pk2(v0.w, cs) : pk2(v0.x, v0.y);
        h2 d1 = (g == 3) ? z : pk2(v0.z, v0.w);
        h2 d2 = (g == 3) ? z : pk2(v1.x, v1.y);
        h2 d3 = (g == 3) ? z : pk2(v1.z, v1.w);
        return mk8(h2u(d0), h2u(d1), h2u(d2), h2u(d3));
    };

    xissue(0, xv0A, xv1A, csA);
    xissue(1, xv0B, xv1B, csB);

    const f4v fz = {0.f, 0.f, 0.f, 0.f};
    f4v acc[8];

#define STEP(SV, V0, V1, CS, OG) do {                                           \
    h8 bx = mkbx(V0, V1, CS);                                                   \
    xissue((SV) + 2, V0, V1, CS);        /* refill same set, 2-step distance */ \
    h2 po0{}, po1{}, po2{}, po3{};                                              \
    _Pragma("unroll")                                                           \
    for (int kb = 0; kb < 5; ++kb) {                                            \
        h8 bv = (kb < 4) ? bf[kb] : bx;                                         \
        _Pragma("unroll")                                                       \
        for (int it = 0; it < 8; ++it)                                          \
            acc[it] = __builtin_amdgcn_mfma_f32_16x16x32_f16(                   \
                af[it][kb], bv, kb == 0 ? fz : acc[it], 0, 0, 0);               \
        po0 += __builtin_shufflevector(bv, bv, 0, 1) * __builtin_shufflevector(wof[kb], wof[kb], 0, 1); \
        po1 += __builtin_shufflevector(bv, bv, 2, 3) * __builtin_shufflevector(wof[kb], wof[kb], 2, 3); \
        po2 += __builtin_shufflevector(bv, bv, 4, 5) * __builtin_shufflevector(wof[kb], wof[kb], 4, 5); \
        po3 += __builtin_shufflevector(bv, bv, 6, 7) * __builtin_shufflevector(wof[kb], wof[kb], 6, 7); \
    }                                                                           \
    { h2 pa = po0 + po1, pb = po2 + po3, pc = pa + pb;                          \
      OG = (float)pc[0] + (float)pc[1]; }                                       \
    if ((SV) < S_ - 1) {                                                        \
        _Pragma("unroll")                                                       \
        for (int it = 0; it < 8; ++it) {                                        \
            uint2 pw;                                                           \
            pw.x = h2u(pk2(acc[it][0], acc[it][1]));                            \
            pw.y = h2u(pk2(acc[it][2], acc[it][3]));                            \
            *reinterpret_cast<uint2*>(wbase + it * 8) = pw;                     \
        }                                                                       \
        _Pragma("unroll")                                                       \
        for (int kb = 0; kb < 4; ++kb)                                          \
            bf[kb] = *reinterpret_cast<const h8*>(rbase + kb * 16);             \
    }                                                                           \
} while (0)

    for (int s4 = 0; s4 < S_; s4 += 4) {
        float og0, og1, og2, og3;
        STEP(s4 + 0, xv0A, xv1A, csA, og0);
        STEP(s4 + 1, xv0B, xv1B, csB, og1);
        STEP(s4 + 2, xv0A, xv1A, csA, og2);
        STEP(s4 + 3, xv0B, xv1B, csB, og3);
        // reduce out partials over the 4 g-groups and store (batched)
        og0 += __shfl_xor(og0, 16, 64);  og0 += __shfl_xor(og0, 32, 64);
        og1 += __shfl_xor(og1, 16, 64);  og1 += __shfl_xor(og1, 32, 64);
        og2 += __shfl_xor(og2, 16, 64);  og2 += __shfl_xor(og2, 32, 64);
        og3 += __shfl_xor(og3, 16, 64);  og3 += __shfl_xor(og3, 32, 64);
        if (g == 0) {
            float* op = outs + (long)(b * S_ + s4) * R_ + r0 + c;
            op[0]      = og0;
            op[R_]     = og1;
            op[2 * R_] = og2;
            op[3 * R_] = og3;
        }
    }
#undef STEP

    // ---- h_final from step-127 accumulators (fp32, D layout: i = it*16+g*4+j) ----
#pragma unroll
    for (int it = 0; it < 8; ++it)
        *reinterpret_cast<f4v*>(
            &hfin[((long)(b * R_ + r0 + c)) * H_ + it * 16 + g * 4]) = acc[it];
}

// ---------------------------------------------------------------------------
extern "C" void kernel_launch(void* const* d_in, const int* in_sizes, int n_in,
                              void* d_out, int out_size, void* d_ws, size_t ws_size,
                              hipStream_t stream)
{
    const float* x      = (const float*)d_in[0];
    const float* hidden = (const float*)d_in[1];
    const float* cost   = (const float*)d_in[2];
    const float* Wo1    = (const float*)d_in[3];
    const float* Wo2    = (const float*)d_in[4];
    const float* Wh1    = (const float*)d_in[5];
    const float* Wh2    = (const float*)d_in[6];

    float* outs = (float*)d_out;                    // [B,S,R]
    float* hfin = outs + (long)B_ * S_ * R_;        // [B,R,H]

    _Float16* WTP = (_Float16*)d_ws;                // [128][160]
    _Float16* woP = WTP + (size_t)H_ * KP;          // [160]

    prep_kernel<<<KP + 1, 128, 0, stream>>>(Wo1, Wo2, Wh1, Wh2, WTP, woP);
    rnn_main<<<1024, 64, 0, stream>>>(x, hidden, cost, WTP, woP, outs, hfin);
}

// Round 10
// 92.479 us; speedup vs baseline: 1.7930x; 1.2535x over previous
//
#include <hip/hip_runtime.h>

#define B_   16
#define S_   128
#define R_   1024
#define KIN  25
#define H_   128
#define MID  256
#define KP   160     // weight K stride (5 slabs of 32)

typedef _Float16 h8 __attribute__((ext_vector_type(8)));
typedef _Float16 h2 __attribute__((ext_vector_type(2)));
typedef float    f4v __attribute__((ext_vector_type(4)));

__device__ __forceinline__ h2 pk2(float a, float b) {
    auto r = __builtin_amdgcn_cvt_pkrtz(a, b);
    h2 o; o[0] = (_Float16)r[0]; o[1] = (_Float16)r[1]; return o;
}
__device__ __forceinline__ unsigned h2u(h2 v) {
    union { h2 h; unsigned u; } c; c.h = v; return c.u;
}
__device__ __forceinline__ h8 mk8(unsigned a, unsigned b, unsigned c, unsigned d) {
    union { h8 v; unsigned u[4]; } r; r.u[0] = a; r.u[1] = b; r.u[2] = c; r.u[3] = d;
    return r.v;
}

// inter k-order: [h(0..127) | x(128..152) | c(153) | pad(154..159)]
__device__ __forceinline__ int orig_k(int kp) {
    if (kp < H_)        return KIN + kp;
    if (kp < H_ + KIN)  return kp - H_;
    if (kp == H_ + KIN) return H_ + KIN;
    return -1;
}

// ---------------------------------------------------------------------------
__global__ void prep_kernel(const float* __restrict__ Wo1, const float* __restrict__ Wo2,
                            const float* __restrict__ Wh1, const float* __restrict__ Wh2,
                            _Float16* __restrict__ WTP, _Float16* __restrict__ woP)
{
    const int kp = blockIdx.x;
    const int t  = threadIdx.x;            // 128 threads
    if (kp < KP) {
        const int ok = orig_k(kp);
        float acc = 0.f;
        if (ok >= 0) {
            const float* w1 = Wh1 + (long)ok * MID;
            for (int m = 0; m < MID; ++m)
                acc += w1[m] * Wh2[m * H_ + t];
        }
        WTP[t * KP + kp] = (_Float16)acc;
    } else {
#pragma unroll
        for (int r = 0; r < 2; ++r) {
            int k2 = t + r * 128;
            if (k2 < KP) {
                int ok = orig_k(k2);
                float acc = 0.f;
                if (ok >= 0)
                    for (int m = 0; m < MID; ++m)
                        acc += Wo1[ok * MID + m] * Wo2[m];
                woP[k2] = (_Float16)acc;
            }
        }
    }
}

// ---------------------------------------------------------------------------
// 1024 blocks x 64 thr (1 wave/SIMD, full chip). Wave owns a 16-row chain.
// Recurrence is 100% in registers: MFMA D -> pk2 -> permlane32/16_swap -> next
// B-frag. out via a 9th MFMA tile (A row0 = wo). No LDS in the h-path, no
// SMEM in the loop (cost via per-block LDS table), no barriers.
// ---------------------------------------------------------------------------
__global__ __launch_bounds__(64, 1) void rnn_main(
    const float* __restrict__ x, const float* __restrict__ hidden,
    const float* __restrict__ cost, const _Float16* __restrict__ WTP,
    const _Float16* __restrict__ woP, float* __restrict__ outs,
    float* __restrict__ hfin)
{
    __shared__ float costS[136];          // 128 + pad (OOB-safe prefetch)

    const int t = threadIdx.x;
    const int c = t & 15, g = t >> 4;
    const int b  = blockIdx.x >> 6;
    const int r0 = (blockIdx.x & 63) << 4;

    // ---- weights into registers: A-frag lane (c,g) = W[m=it*16+c][kb*32+g*8+u] ----
    h8 af[8][5];
#pragma unroll
    for (int it = 0; it < 8; ++it)
#pragma unroll
        for (int kb = 0; kb < 5; ++kb)
            af[it][kb] = *reinterpret_cast<const h8*>(
                &WTP[(it * 16 + c) * KP + kb * 32 + g * 8]);
    h8 wz;
#pragma unroll
    for (int u = 0; u < 8; ++u) wz[u] = (_Float16)0.f;
    h8 afo[5];                            // out tile: A row 0 = wo, rest 0
#pragma unroll
    for (int kb = 0; kb < 5; ++kb) {
        h8 w = *reinterpret_cast<const h8*>(&woP[kb * 32 + g * 8]);
        afo[kb] = (c == 0) ? w : wz;
    }

    // ---- per-block cost table (keeps SMEM out of the loop) ----
    costS[t]      = cost[b * S_ + t];
    costS[t + 64] = cost[b * S_ + t + 64];
    if (t < 8) costS[128 + t] = 0.f;

    // ---- h(0) -> bf in B-frag layout: lane (c,g) = inter[row c][kb*32+g*8+u] ----
    h8 bf[4];
    {
        const float* hp = hidden + ((long)(b * R_ + r0 + c)) * H_;
#pragma unroll
        for (int kb = 0; kb < 4; ++kb) {
            float4 v0 = *reinterpret_cast<const float4*>(hp + kb * 32 + g * 8);
            float4 v1 = *reinterpret_cast<const float4*>(hp + kb * 32 + g * 8 + 4);
            bf[kb] = mk8(h2u(pk2(v0.x, v0.y)), h2u(pk2(v0.z, v0.w)),
                         h2u(pk2(v1.x, v1.y)), h2u(pk2(v1.z, v1.w)));
        }
    }

    // ---- x pipeline: lane (c,g) loads its own B-frag slice, 4-step distance ----
    const int xoff  = (g == 3) ? 21 : g * 8;     // g=3 reads x[21..24] (use .w)
    const int xoff2 = (g == 3) ? 0 : 4;
    const float* xlane = x + (((long)b * S_) * R_ + r0 + c) * KIN + xoff;

    float4 X0a, X0b, X1a, X1b, X2a, X2b, X3a, X3b;
    auto xinit = [&](int s, float4& v0, float4& v1) {
        const float* p = xlane + (long)s * (R_ * KIN);
        v0 = *reinterpret_cast<const float4*>(p);
        v1 = *reinterpret_cast<const float4*>(p + xoff2);
    };
    xinit(0, X0a, X0b); xinit(1, X1a, X1b); xinit(2, X2a, X2b); xinit(3, X3a, X3b);

    auto mkbx = [&](float4 v0, float4 v1, float cs) -> h8 {
        h2 z{};
        h2 d0 = (g == 3) ? pk2(v0.w, cs) : pk2(v0.x, v0.y);
        h2 d1 = (g == 3) ? z : pk2(v0.z, v0.w);
        h2 d2 = (g == 3) ? z : pk2(v1.x, v1.y);
        h2 d3 = (g == 3) ? z : pk2(v1.z, v1.w);
        return mk8(h2u(d0), h2u(d1), h2u(d2), h2u(d3));
    };

    const f4v fz = {0.f, 0.f, 0.f, 0.f};
    f4v acc[8], acco = fz;
    float4 ccA = *reinterpret_cast<const float4*>(&costS[0]);
    float4 ccB;

#define STEP(SV, XV0, XV1, CSV, OG) do {                                        \
    h8 bx = mkbx(XV0, XV1, CSV);                                                \
    if ((SV) + 4 < S_) {                                                        \
        const float* p_ = xlane + (long)((SV) + 4) * (R_ * KIN);                \
        XV0 = *reinterpret_cast<const float4*>(p_);                             \
        XV1 = *reinterpret_cast<const float4*>(p_ + xoff2);                     \
    }                                                                           \
    _Pragma("unroll")                                                           \
    for (int kb = 0; kb < 5; ++kb) {                                            \
        h8 bv = (kb < 4) ? bf[kb] : bx;                                         \
        _Pragma("unroll")                                                       \
        for (int it = 0; it < 8; ++it)                                          \
            acc[it] = __builtin_amdgcn_mfma_f32_16x16x32_f16(                   \
                af[it][kb], bv, kb == 0 ? fz : acc[it], 0, 0, 0);               \
        acco = __builtin_amdgcn_mfma_f32_16x16x32_f16(                          \
            afo[kb], bv, kb == 0 ? fz : acco, 0, 0, 0);                         \
    }                                                                           \
    OG = acco[0];                       /* D row 0 lives in g==0 lanes, reg 0 */\
    if ((SV) < S_ - 1) {                                                        \
        _Pragma("unroll")                                                       \
        for (int kb = 0; kb < 4; ++kb) {                                        \
            unsigned A0 = h2u(pk2(acc[2*kb][0],   acc[2*kb][1]));               \
            unsigned A1 = h2u(pk2(acc[2*kb][2],   acc[2*kb][3]));               \
            unsigned B0 = h2u(pk2(acc[2*kb+1][0], acc[2*kb+1][1]));             \
            unsigned B1 = h2u(pk2(acc[2*kb+1][2], acc[2*kb+1][3]));             \
            auto r0_ = __builtin_amdgcn_permlane32_swap(A0, B0, false, false);  \
            auto q0_ = __builtin_amdgcn_permlane16_swap(r0_[0], r0_[1], false, false); \
            auto r1_ = __builtin_amdgcn_permlane32_swap(A1, B1, false, false);  \
            auto q1_ = __builtin_amdgcn_permlane16_swap(r1_[0], r1_[1], false, false); \
            bf[kb] = mk8(q0_[0], q1_[0], q0_[1], q1_[1]);                       \
        }                                                                       \
    }                                                                           \
} while (0)

    for (int s4 = 0; s4 < S_; s4 += 8) {
        float og0, og1, og2, og3;
        ccB = *reinterpret_cast<const float4*>(&costS[s4 + 4]);
        STEP(s4 + 0, X0a, X0b, ccA[0], og0);
        STEP(s4 + 1, X1a, X1b, ccA[1], og1);
        STEP(s4 + 2, X2a, X2b, ccA[2], og2);
        STEP(s4 + 3, X3a, X3b, ccA[3], og3);
        if (g == 0) {
            float* op = outs + (long)(b * S_ + s4) * R_ + r0 + c;
            op[0] = og0; op[R_] = og1; op[2 * R_] = og2; op[3 * R_] = og3;
        }
        ccA = *reinterpret_cast<const float4*>(&costS[s4 + 8]);   // pad-safe
        STEP(s4 + 4, X0a, X0b, ccB[0], og0);
        STEP(s4 + 5, X1a, X1b, ccB[1], og1);
        STEP(s4 + 6, X2a, X2b, ccB[2], og2);
        STEP(s4 + 7, X3a, X3b, ccB[3], og3);
        if (g == 0) {
            float* op = outs + (long)(b * S_ + s4 + 4) * R_ + r0 + c;
            op[0] = og0; op[R_] = og1; op[2 * R_] = og2; op[3 * R_] = og3;
        }
    }
#undef STEP

    // ---- h_final from step-127 accumulators (fp32, D layout i = it*16+g*4+j) ----
#pragma unroll
    for (int it = 0; it < 8; ++it)
        *reinterpret_cast<f4v*>(
            &hfin[((long)(b * R_ + r0 + c)) * H_ + it * 16 + g * 4]) = acc[it];
}

// ---------------------------------------------------------------------------
extern "C" void kernel_launch(void* const* d_in, const int* in_sizes, int n_in,
                              void* d_out, int out_size, void* d_ws, size_t ws_size,
                              hipStream_t stream)
{
    const float* x      = (const float*)d_in[0];
    const float* hidden = (const float*)d_in[1];
    const float* cost   = (const float*)d_in[2];
    const float* Wo1    = (const float*)d_in[3];
    const float* Wo2    = (const float*)d_in[4];
    const float* Wh1    = (const float*)d_in[5];
    const float* Wh2    = (const float*)d_in[6];

    float* outs = (float*)d_out;                    // [B,S,R]
    float* hfin = outs + (long)B_ * S_ * R_;        // [B,R,H]

    _Float16* WTP = (_Float16*)d_ws;                // [128][160]
    _Float16* woP = WTP + (size_t)H_ * KP;          // [160]

    prep_kernel<<<KP + 1, 128, 0, stream>>>(Wo1, Wo2, Wh1, Wh2, WTP, woP);
    rnn_main<<<1024, 64, 0, stream>>>(x, hidden, cost, WTP, woP, outs, hfin);
}